// Round 1
// baseline (649.145 us; speedup 1.0000x reference)
//
#include <hip/hip_runtime.h>
#include <math.h>

#define NROWS 2000000
#define IN_DIM 64
#define HID 128

// tanh(a) = 1 - 2/(exp(2a)+1)  -- NaN-free for a -> +/-inf
__device__ __forceinline__ float fast_tanh(float a) {
    float e2a = __expf(2.0f * a);
    return 1.0f - 2.0f / (e2a + 1.0f);
}

__global__ void zero_sums_kernel(float* g) {
    if (threadIdx.x < 2) g[threadIdx.x] = 0.0f;
}

__global__ __launch_bounds__(256) void fused_fwd_kernel(
    const float* __restrict__ x, const int* __restrict__ T,
    const float* __restrict__ W1, const float* __restrict__ b1,
    const float* __restrict__ W2, const float* __restrict__ b2,
    float* __restrict__ e_out, float* __restrict__ gsums)
{
    const float b2v = b2[0];
    const int tid = blockIdx.x * blockDim.x + threadIdx.x;
    const int stride = gridDim.x * blockDim.x;

    float ls0 = 0.0f, ls1 = 0.0f;

    for (int i = tid; i < NROWS; i += stride) {
        // Load x row (64 f32) into registers via float4 loads.
        float xr[IN_DIM];
        const float4* xp = reinterpret_cast<const float4*>(x + (size_t)i * IN_DIM);
        #pragma unroll
        for (int q = 0; q < IN_DIM / 4; ++q) {
            float4 v = xp[q];
            xr[4*q+0] = v.x; xr[4*q+1] = v.y; xr[4*q+2] = v.z; xr[4*q+3] = v.w;
        }

        float s = b2v;
        // j loop: W1 row j is loop-uniform -> compiler scalarizes to s_load,
        // v_fmac_f32 takes the SGPR operand directly.
        #pragma unroll 2
        for (int j = 0; j < HID; ++j) {
            const float* __restrict__ w = W1 + j * IN_DIM;
            float a0 = 0.f, a1 = 0.f, a2 = 0.f, a3 = 0.f;
            #pragma unroll
            for (int k = 0; k < IN_DIM; k += 4) {
                a0 = fmaf(xr[k+0], w[k+0], a0);
                a1 = fmaf(xr[k+1], w[k+1], a1);
                a2 = fmaf(xr[k+2], w[k+2], a2);
                a3 = fmaf(xr[k+3], w[k+3], a3);
            }
            float acc = (a0 + a1) + (a2 + a3) + b1[j];
            s = fmaf(fast_tanh(acc), W2[j], s);
        }

        float e = __expf(s);
        e_out[i] = e;
        if (T[i] == 0) ls0 += e; else ls1 += e;
    }

    // Wave-level butterfly reduce (64 lanes), then one atomic per wave/group.
    #pragma unroll
    for (int off = 32; off > 0; off >>= 1) {
        ls0 += __shfl_down(ls0, off, 64);
        ls1 += __shfl_down(ls1, off, 64);
    }
    if ((threadIdx.x & 63) == 0) {
        atomicAdd(&gsums[0], ls0);
        atomicAdd(&gsums[1], ls1);
    }
}

__global__ __launch_bounds__(256) void normalize_kernel(
    float* __restrict__ e_out, const int* __restrict__ T,
    const float* __restrict__ gsums)
{
    const float inv0 = 1.0f / gsums[0];
    const float inv1 = 1.0f / gsums[1];
    const int n4 = NROWS / 4;
    const int stride = gridDim.x * blockDim.x;
    for (int i = blockIdx.x * blockDim.x + threadIdx.x; i < n4; i += stride) {
        float4 e = reinterpret_cast<const float4*>(e_out)[i];
        int4  t = reinterpret_cast<const int4*>(T)[i];
        e.x *= (t.x == 0) ? inv0 : inv1;
        e.y *= (t.y == 0) ? inv0 : inv1;
        e.z *= (t.z == 0) ? inv0 : inv1;
        e.w *= (t.w == 0) ? inv0 : inv1;
        reinterpret_cast<float4*>(e_out)[i] = e;
    }
}

extern "C" void kernel_launch(void* const* d_in, const int* in_sizes, int n_in,
                              void* d_out, int out_size, void* d_ws, size_t ws_size,
                              hipStream_t stream) {
    const float* x  = (const float*)d_in[0];
    const int*   T  = (const int*)d_in[1];
    const float* W1 = (const float*)d_in[2];
    const float* b1 = (const float*)d_in[3];
    const float* W2 = (const float*)d_in[4];
    const float* b2 = (const float*)d_in[5];
    float* e_out = (float*)d_out;
    float* gsums = (float*)d_ws;   // 2 floats of scratch

    zero_sums_kernel<<<1, 64, 0, stream>>>(gsums);

    const int blocks = 2048;
    fused_fwd_kernel<<<blocks, 256, 0, stream>>>(x, T, W1, b1, W2, b2, e_out, gsums);

    normalize_kernel<<<2048, 256, 0, stream>>>(e_out, T, gsums);
}

// Round 2
// 199.112 us; speedup vs baseline: 3.2602x; 3.2602x over previous
//
#include <hip/hip_runtime.h>
#include <math.h>

#define NROWS 2000000
#define IN_DIM 64
#define HID 128
#define NTILES (NROWS / 16)

typedef __bf16 bf16x8 __attribute__((ext_vector_type(8)));
typedef float f32x4 __attribute__((ext_vector_type(4)));

// tanh(a) = 1 - 2/(exp(2a)+1); v_exp + v_rcp (1-ulp each), NaN-free at +/-inf
__device__ __forceinline__ float tanh_fast(float a) {
    float p = __expf(2.0f * a);
    float r = __builtin_amdgcn_rcpf(p + 1.0f);
    return fmaf(-2.0f, r, 1.0f);
}

// Split 8 fp32 (two f32x4) into hi/lo bf16x8 fragments: v = hi + lo + O(2^-18 |v|)
__device__ __forceinline__ void split8(f32x4 a, f32x4 b, bf16x8& h, bf16x8& l) {
    #pragma unroll
    for (int j = 0; j < 4; j++) {
        __bf16 hb = (__bf16)a[j];
        h[j] = hb;
        l[j] = (__bf16)(a[j] - (float)hb);
    }
    #pragma unroll
    for (int j = 0; j < 4; j++) {
        __bf16 hb = (__bf16)b[j];
        h[4 + j] = hb;
        l[4 + j] = (__bf16)(b[j] - (float)hb);
    }
}

__global__ void zero_sums_kernel(float* g) {
    if (threadIdx.x < 2) g[threadIdx.x] = 0.0f;
}

__global__ __launch_bounds__(256, 2) void fused_mfma_kernel(
    const float* __restrict__ x, const int* __restrict__ T,
    const float* __restrict__ W1, const float* __restrict__ b1,
    const float* __restrict__ W2, const float* __restrict__ b2,
    float* __restrict__ e_out, float* __restrict__ gsums)
{
    const int lane = threadIdx.x & 63;
    const int c16  = lane & 15;   // row-in-tile for A; hidden-residue for B/C
    const int g4   = lane >> 4;   // k-octet select; row-group for C
    const int gwave = blockIdx.x * (blockDim.x >> 6) + (threadIdx.x >> 6);
    const int nwave = gridDim.x * (blockDim.x >> 6);

    // ---- prefetch first x tile (A-frag source): row = tile*16 + c16, k = g4*8 + c*32 ----
    int tile = gwave;
    f32x4 xq0, xq1, xq2, xq3;
    {
        const float* xp = x + (size_t)(tile * 16 + c16) * IN_DIM + g4 * 8;
        xq0 = *(const f32x4*)(xp);
        xq1 = *(const f32x4*)(xp + 4);
        xq2 = *(const f32x4*)(xp + 32);
        xq3 = *(const f32x4*)(xp + 36);
    }

    // ---- W1 fragments, bf16-split, resident in registers (32 frags = 128 VGPR) ----
    // B[k][n] = W1[n][k]; lane: n = t*16 + c16, k = c*32 + g4*8 + j
    bf16x8 w1h[8][2], w1l[8][2];
    #pragma unroll
    for (int t = 0; t < 8; t++) {
        #pragma unroll
        for (int c = 0; c < 2; c++) {
            const float* wp = W1 + (size_t)(t * 16 + c16) * IN_DIM + c * 32 + g4 * 8;
            f32x4 a = *(const f32x4*)wp;
            f32x4 b = *(const f32x4*)(wp + 4);
            split8(a, b, w1h[t][c], w1l[t][c]);
        }
    }
    float b1v[8], w2v[8];
    #pragma unroll
    for (int t = 0; t < 8; t++) {
        b1v[t] = b1[t * 16 + c16];
        w2v[t] = W2[t * 16 + c16];
    }
    const float b2v = b2[0];

    float ls0 = 0.f, ls1 = 0.f;

    for (; tile < NTILES; tile += nwave) {
        // convert current x tile to bf16-split A fragments
        bf16x8 xh0, xh1, xl0, xl1;
        split8(xq0, xq1, xh0, xl0);
        split8(xq2, xq3, xh1, xl1);

        // prefetch next tile (overlaps MFMA + epilogue below)
        int nt = tile + nwave;
        if (nt < NTILES) {
            const float* xp = x + (size_t)(nt * 16 + c16) * IN_DIM + g4 * 8;
            xq0 = *(const f32x4*)(xp);
            xq1 = *(const f32x4*)(xp + 4);
            xq2 = *(const f32x4*)(xp + 32);
            xq3 = *(const f32x4*)(xp + 36);
        }

        // h = x @ W1.T via 4-product bf16-split MFMA (fp32-accurate)
        f32x4 acc[8];
        #pragma unroll
        for (int t = 0; t < 8; t++) acc[t] = (f32x4){0.f, 0.f, 0.f, 0.f};
        #pragma unroll
        for (int t = 0; t < 8; t++) {
            acc[t] = __builtin_amdgcn_mfma_f32_16x16x32_bf16(xh0, w1h[t][0], acc[t], 0, 0, 0);
            acc[t] = __builtin_amdgcn_mfma_f32_16x16x32_bf16(xl0, w1h[t][0], acc[t], 0, 0, 0);
            acc[t] = __builtin_amdgcn_mfma_f32_16x16x32_bf16(xh0, w1l[t][0], acc[t], 0, 0, 0);
            acc[t] = __builtin_amdgcn_mfma_f32_16x16x32_bf16(xl0, w1l[t][0], acc[t], 0, 0, 0);
            acc[t] = __builtin_amdgcn_mfma_f32_16x16x32_bf16(xh1, w1h[t][1], acc[t], 0, 0, 0);
            acc[t] = __builtin_amdgcn_mfma_f32_16x16x32_bf16(xl1, w1h[t][1], acc[t], 0, 0, 0);
            acc[t] = __builtin_amdgcn_mfma_f32_16x16x32_bf16(xh1, w1l[t][1], acc[t], 0, 0, 0);
            acc[t] = __builtin_amdgcn_mfma_f32_16x16x32_bf16(xl1, w1l[t][1], acc[t], 0, 0, 0);
        }

        // epilogue: bias + tanh + W2 partials.
        // C layout: lane holds h[row=(g4*4+r)][col=t*16+c16], r = reg 0..3
        float sp0 = 0.f, sp1 = 0.f, sp2 = 0.f, sp3 = 0.f;
        #pragma unroll
        for (int t = 0; t < 8; t++) {
            sp0 = fmaf(tanh_fast(acc[t][0] + b1v[t]), w2v[t], sp0);
            sp1 = fmaf(tanh_fast(acc[t][1] + b1v[t]), w2v[t], sp1);
            sp2 = fmaf(tanh_fast(acc[t][2] + b1v[t]), w2v[t], sp2);
            sp3 = fmaf(tanh_fast(acc[t][3] + b1v[t]), w2v[t], sp3);
        }
        // reduce over the 16 hidden-residue lanes (butterfly within 16-lane groups)
        #pragma unroll
        for (int m = 1; m < 16; m <<= 1) {
            sp0 += __shfl_xor(sp0, m, 16);
            sp1 += __shfl_xor(sp1, m, 16);
            sp2 += __shfl_xor(sp2, m, 16);
            sp3 += __shfl_xor(sp3, m, 16);
        }
        // lanes c16<4 own rows g4*4 + c16
        if (c16 < 4) {
            float sv = (c16 == 0) ? sp0 : (c16 == 1) ? sp1 : (c16 == 2) ? sp2 : sp3;
            float e = __expf(sv + b2v);
            int row = tile * 16 + g4 * 4 + c16;
            e_out[row] = e;
            if (T[row] == 0) ls0 += e; else ls1 += e;
        }
    }

    // per-wave reduce, then one atomic pair per wave (4096 total)
    #pragma unroll
    for (int off = 32; off > 0; off >>= 1) {
        ls0 += __shfl_down(ls0, off, 64);
        ls1 += __shfl_down(ls1, off, 64);
    }
    if (lane == 0) {
        atomicAdd(&gsums[0], ls0);
        atomicAdd(&gsums[1], ls1);
    }
}

__global__ __launch_bounds__(256) void normalize_kernel(
    float* __restrict__ e_out, const int* __restrict__ T,
    const float* __restrict__ gsums)
{
    const float inv0 = 1.0f / gsums[0];
    const float inv1 = 1.0f / gsums[1];
    const int n4 = NROWS / 4;
    const int stride = gridDim.x * blockDim.x;
    for (int i = blockIdx.x * blockDim.x + threadIdx.x; i < n4; i += stride) {
        float4 e = reinterpret_cast<const float4*>(e_out)[i];
        int4  t = reinterpret_cast<const int4*>(T)[i];
        e.x *= (t.x == 0) ? inv0 : inv1;
        e.y *= (t.y == 0) ? inv0 : inv1;
        e.z *= (t.z == 0) ? inv0 : inv1;
        e.w *= (t.w == 0) ? inv0 : inv1;
        reinterpret_cast<float4*>(e_out)[i] = e;
    }
}

extern "C" void kernel_launch(void* const* d_in, const int* in_sizes, int n_in,
                              void* d_out, int out_size, void* d_ws, size_t ws_size,
                              hipStream_t stream) {
    const float* x  = (const float*)d_in[0];
    const int*   T  = (const int*)d_in[1];
    const float* W1 = (const float*)d_in[2];
    const float* b1 = (const float*)d_in[3];
    const float* W2 = (const float*)d_in[4];
    const float* b2 = (const float*)d_in[5];
    float* e_out = (float*)d_out;
    float* gsums = (float*)d_ws;

    zero_sums_kernel<<<1, 64, 0, stream>>>(gsums);

    // 512 blocks x 256 thr = 2048 waves; ~224 VGPR -> 2 waves/SIMD, 2 blocks/CU,
    // all blocks resident from t=0 (grid-stride is statically partitioned).
    fused_mfma_kernel<<<512, 256, 0, stream>>>(x, T, W1, b1, W2, b2, e_out, gsums);

    normalize_kernel<<<2048, 256, 0, stream>>>(e_out, T, gsums);
}